// Round 1
// baseline (120.020 us; speedup 1.0000x reference)
//
#include <hip/hip_runtime.h>

// Problem constants (match reference setup_inputs)
constexpr int N  = 4096;   // node groups
constexpr int C  = 64;     // children per node
constexpr int B  = 256;    // batch
constexpr int NN = 8192;   // node_mars rows

// One block per node group; 256 threads = batch dimension.
// Lane b reads element_mars[cid*B + b] -> coalesced across the wave.
// cids/params are uniform per child -> staged in LDS once per block.
// All 64 gathered values kept live in VGPRs: single gather pass,
// exact two-phase logsumexp (max, then sum of exp).
__global__ __launch_bounds__(256) void sum_layer_kernel(
    const float* __restrict__ element_mars,
    const float* __restrict__ params,
    const int*   __restrict__ nids,
    const int*   __restrict__ cids,
    const int*   __restrict__ pids,
    float*       __restrict__ out)
{
    __shared__ int   s_off[C];   // cid * B (row base offset in elements)
    __shared__ float s_w[C];     // params[pids[n,c]]

    const int n = blockIdx.x;
    const int t = threadIdx.x;

    if (t < C) {
        s_off[t] = cids[n * C + t] * B;
        s_w[t]   = params[pids[n * C + t]];
    }
    __syncthreads();

    const int b = t;

    float v[C];
    float m = -INFINITY;
    #pragma unroll
    for (int c = 0; c < C; ++c) {
        v[c] = element_mars[s_off[c] + b];
        m = fmaxf(m, v[c]);
    }

    float s = 0.0f;
    #pragma unroll
    for (int c = 0; c < C; ++c) {
        s += s_w[c] * __expf(v[c] - m);
    }

    out[nids[n] * B + b] = __logf(fmaxf(s, 1e-10f)) + m;
}

extern "C" void kernel_launch(void* const* d_in, const int* in_sizes, int n_in,
                              void* d_out, int out_size, void* d_ws, size_t ws_size,
                              hipStream_t stream) {
    const float* node_mars    = (const float*)d_in[0];
    const float* element_mars = (const float*)d_in[1];
    const float* params       = (const float*)d_in[2];
    const int*   nids         = (const int*)d_in[3];
    const int*   cids         = (const int*)d_in[4];
    const int*   pids         = (const int*)d_in[5];
    float*       out          = (float*)d_out;

    // Rows of node_mars not addressed by nids must pass through unchanged;
    // d_out is re-poisoned before every launch, so copy the whole tensor
    // first, then overwrite the nids rows.
    hipMemcpyAsync(out, node_mars, (size_t)NN * B * sizeof(float),
                   hipMemcpyDeviceToDevice, stream);

    sum_layer_kernel<<<dim3(N), dim3(256), 0, stream>>>(
        element_mars, params, nids, cids, pids, out);
}